// Round 1
// baseline (102.811 us; speedup 1.0000x reference)
//
#include <hip/hip_runtime.h>

#define D 8
#define NE 4
#define NS 3
#define NI 5
#define LN_EPS 1e-5f

// ---------------------------------------------------------------------------
// Setup kernel: C[s][n][d] = bproj[s][d] + sum_ij Bmat[s][n][i][j]*Wproj[s][d][i*8+j]
// Row-independent, 96 values into d_ws.
// ---------------------------------------------------------------------------
__global__ void precompute_C_kernel(const float* __restrict__ Bmat,
                                    const float* __restrict__ Wproj,
                                    const float* __restrict__ bproj,
                                    float* __restrict__ C) {
    int idx = threadIdx.x;
    if (idx >= NS * NE * D) return;
    int s = idx / (NE * D);
    int rem = idx % (NE * D);
    int n = rem / D;
    int d = rem % D;
    const float* bm = Bmat + ((size_t)s * NE + n) * 64;
    const float* wp = Wproj + ((size_t)s * D + d) * 64;
    float acc = bproj[s * D + d];
    #pragma unroll
    for (int k = 0; k < 64; ++k) acc += bm[k] * wp[k];
    C[idx] = acc;
}

// ---------------------------------------------------------------------------
// Main kernel: one thread per row. All per-row state in registers.
// Weights are read through wave-uniform addresses (compiler emits s_load).
// Outputs staged via LDS for coalesced global stores.
// ---------------------------------------------------------------------------
__global__ __launch_bounds__(256, 2) void whisp_kernel(
    const float* __restrict__ cl, const float* __restrict__ cd,
    const float* __restrict__ re_log, const float* __restrict__ mach,
    const float* __restrict__ alpha, const float* __restrict__ u,
    const float* __restrict__ We, const float* __restrict__ be,
    const float* __restrict__ Wproj,
    const float* __restrict__ Wr1, const float* __restrict__ br1,
    const float* __restrict__ Wr2, const float* __restrict__ br2,
    const float* __restrict__ ln_g, const float* __restrict__ ln_b,
    const float* __restrict__ Wout, const float* __restrict__ bout,
    const float* __restrict__ fg, const float* __restrict__ fb,
    const float* __restrict__ Wcst, const float* __restrict__ bcst,
    const float* __restrict__ Wcl, const float* __restrict__ bcl,
    const float* __restrict__ Cpre,
    float* __restrict__ out, int B)
{
    __shared__ float souts[256 * 19];

    const int tid = threadIdx.x;
    const int row = blockIdx.x * 256 + tid;

    if (row < B) {
        // ---- per-row inputs ----
        float uu[D];
        {
            const float4* up = reinterpret_cast<const float4*>(u + (size_t)row * D);
            float4 u0 = up[0], u1 = up[1];
            uu[0] = u0.x; uu[1] = u0.y; uu[2] = u0.z; uu[3] = u0.w;
            uu[4] = u1.x; uu[5] = u1.y; uu[6] = u1.z; uu[7] = u1.w;
        }
        float xs[NE] = { cl[row], cd[row], re_log[row], mach[row] };
        float al = alpha[row];

        // ---- embedding: E[n][d] = tanh(We[n][d][0]*x_n + We[n][d][1]*alpha + be[n][d]) ----
        float E[NE][D];
        #pragma unroll
        for (int n = 0; n < NE; ++n) {
            #pragma unroll
            for (int d = 0; d < D; ++d) {
                float pre = We[n * 16 + d * 2 + 0] * xs[n]
                          + We[n * 16 + d * 2 + 1] * al
                          + be[n * D + d];
                E[n][d] = tanhf(pre);
            }
        }

        // ---- outer stages ----
        for (int s = 0; s < NS; ++s) {
            const float* Wp = Wproj + (size_t)s * D * 64;
            const float* W1 = Wr1 + s * 64;
            const float* B1 = br1 + s * D;
            const float* W2 = Wr2 + s * (NE * D);
            const float* B2 = br2 + s * NE;
            const float* Cs = Cpre + s * (NE * D);

            // t[d][i] = sum_j u[j] * Wp[d][i*8+j]   (reused across NI iterations)
            float t[D][D];
            #pragma unroll
            for (int d = 0; d < D; ++d) {
                #pragma unroll
                for (int i = 0; i < D; ++i) {
                    float acc = 0.f;
                    #pragma unroll
                    for (int j = 0; j < D; ++j) acc += uu[j] * Wp[d * 64 + i * 8 + j];
                    t[d][i] = acc;
                }
            }

            for (int it = 0; it < NI; ++it) {
                // H[n][d] = C[n][d] + sum_i E[n][i]*t[d][i]
                float H[NE][D];
                #pragma unroll
                for (int n = 0; n < NE; ++n) {
                    #pragma unroll
                    for (int d = 0; d < D; ++d) {
                        float acc = Cs[n * D + d];
                        #pragma unroll
                        for (int i = 0; i < D; ++i) acc += E[n][i] * t[d][i];
                        H[n][d] = acc;
                    }
                }
                // routing: sm[n][e] = softmax_e( relu(H[n]@W1.T+b1) @ W2.T + b2 )
                float sm[NE][NE];
                #pragma unroll
                for (int n = 0; n < NE; ++n) {
                    float r[D];
                    #pragma unroll
                    for (int d = 0; d < D; ++d) {
                        float acc = B1[d];
                        #pragma unroll
                        for (int k = 0; k < D; ++k) acc += H[n][k] * W1[d * D + k];
                        r[d] = fmaxf(acc, 0.f);
                    }
                    float lg[NE];
                    #pragma unroll
                    for (int e = 0; e < NE; ++e) {
                        float acc = B2[e];
                        #pragma unroll
                        for (int k = 0; k < D; ++k) acc += r[k] * W2[e * D + k];
                        lg[e] = acc;
                    }
                    float mx = fmaxf(fmaxf(lg[0], lg[1]), fmaxf(lg[2], lg[3]));
                    float e0 = __expf(lg[0] - mx), e1 = __expf(lg[1] - mx);
                    float e2 = __expf(lg[2] - mx), e3 = __expf(lg[3] - mx);
                    float inv = 1.f / (e0 + e1 + e2 + e3);
                    sm[n][0] = e0 * inv; sm[n][1] = e1 * inv;
                    sm[n][2] = e2 * inv; sm[n][3] = e3 * inv;
                }
                // E += mix, mix[n][d] = sum_e sm[n][e]*H[e][d]
                #pragma unroll
                for (int n = 0; n < NE; ++n) {
                    #pragma unroll
                    for (int d = 0; d < D; ++d) {
                        E[n][d] += sm[n][0] * H[0][d] + sm[n][1] * H[1][d]
                                 + sm[n][2] * H[2][d] + sm[n][3] * H[3][d];
                    }
                }
            }

            // post-stage LayerNorm per embedding n
            #pragma unroll
            for (int n = 0; n < NE; ++n) {
                float m = 0.f;
                #pragma unroll
                for (int d = 0; d < D; ++d) m += E[n][d];
                m *= (1.f / D);
                float v = 0.f;
                #pragma unroll
                for (int d = 0; d < D; ++d) { float c = E[n][d] - m; v += c * c; }
                v *= (1.f / D);
                float inv = rsqrtf(v + LN_EPS);
                #pragma unroll
                for (int d = 0; d < D; ++d)
                    E[n][d] = (E[n][d] - m) * inv * ln_g[d] + ln_b[d];
            }
        }

        // ---- final mixing: w = softmax(Eflat @ Wout.T + bout) ----
        float lg[NE];
        #pragma unroll
        for (int e = 0; e < NE; ++e) {
            float acc = bout[e];
            #pragma unroll
            for (int n = 0; n < NE; ++n) {
                #pragma unroll
                for (int d = 0; d < D; ++d) acc += E[n][d] * Wout[e * 32 + n * D + d];
            }
            lg[e] = acc;
        }
        float mx = fmaxf(fmaxf(lg[0], lg[1]), fmaxf(lg[2], lg[3]));
        float w0 = __expf(lg[0] - mx), w1 = __expf(lg[1] - mx);
        float w2 = __expf(lg[2] - mx), w3 = __expf(lg[3] - mx);
        float winv = 1.f / (w0 + w1 + w2 + w3);
        w0 *= winv; w1 *= winv; w2 *= winv; w3 *= winv;

        // z = LN( sum_n w[n]*E[n][:] ) with fg, fb
        float z[D];
        #pragma unroll
        for (int d = 0; d < D; ++d)
            z[d] = w0 * E[0][d] + w1 * E[1][d] + w2 * E[2][d] + w3 * E[3][d];
        float zm = 0.f;
        #pragma unroll
        for (int d = 0; d < D; ++d) zm += z[d];
        zm *= (1.f / D);
        float zv = 0.f;
        #pragma unroll
        for (int d = 0; d < D; ++d) { float c = z[d] - zm; zv += c * c; }
        zv *= (1.f / D);
        float zinv = rsqrtf(zv + LN_EPS);
        #pragma unroll
        for (int d = 0; d < D; ++d)
            z[d] = (z[d] - zm) * zinv * fg[d] + fb[d];

        // heads -> stage into LDS
        float* so = &souts[tid * 19];
        #pragma unroll
        for (int k = 0; k < 18; ++k) {
            float acc = bcst[k];
            #pragma unroll
            for (int d = 0; d < D; ++d) acc += z[d] * Wcst[k * D + d];
            so[k] = acc;
        }
        {
            float acc = bcl[0];
            #pragma unroll
            for (int d = 0; d < D; ++d) acc += z[d] * Wcl[d];
            so[18] = acc;
        }
    }

    __syncthreads();

    // coalesced writeback of this block's 256x19 outputs
    const int base = blockIdx.x * 256;
    int nrows = B - base;
    if (nrows > 256) nrows = 256;
    if (nrows > 0) {
        const int cnt = nrows * 19;
        for (int i = tid; i < cnt; i += 256)
            out[(size_t)base * 19 + i] = souts[i];
    }
}

extern "C" void kernel_launch(void* const* d_in, const int* in_sizes, int n_in,
                              void* d_out, int out_size, void* d_ws, size_t ws_size,
                              hipStream_t stream) {
    const float* cl     = (const float*)d_in[0];
    const float* cd     = (const float*)d_in[1];
    const float* re_log = (const float*)d_in[2];
    const float* mach   = (const float*)d_in[3];
    const float* alpha  = (const float*)d_in[4];
    const float* u      = (const float*)d_in[5];
    const float* We     = (const float*)d_in[6];
    const float* be     = (const float*)d_in[7];
    const float* Bmat   = (const float*)d_in[8];
    const float* Wproj  = (const float*)d_in[9];
    const float* bproj  = (const float*)d_in[10];
    const float* Wr1    = (const float*)d_in[11];
    const float* br1    = (const float*)d_in[12];
    const float* Wr2    = (const float*)d_in[13];
    const float* br2    = (const float*)d_in[14];
    const float* ln_g   = (const float*)d_in[15];
    const float* ln_b   = (const float*)d_in[16];
    const float* Wout   = (const float*)d_in[17];
    const float* bout   = (const float*)d_in[18];
    const float* fg     = (const float*)d_in[19];
    const float* fb     = (const float*)d_in[20];
    const float* Wcst   = (const float*)d_in[21];
    const float* bcst   = (const float*)d_in[22];
    const float* Wcl    = (const float*)d_in[23];
    const float* bcl    = (const float*)d_in[24];

    float* Cpre = (float*)d_ws;   // 96 floats
    const int B = in_sizes[0];

    hipLaunchKernelGGL(precompute_C_kernel, dim3(1), dim3(128), 0, stream,
                       Bmat, Wproj, bproj, Cpre);

    const int blocks = (B + 255) / 256;
    hipLaunchKernelGGL(whisp_kernel, dim3(blocks), dim3(256), 0, stream,
                       cl, cd, re_log, mach, alpha, u, We, be, Wproj,
                       Wr1, br1, Wr2, br2, ln_g, ln_b, Wout, bout, fg, fb,
                       Wcst, bcst, Wcl, bcl, Cpre, (float*)d_out, B);
}

// Round 2
// 75.324 us; speedup vs baseline: 1.3649x; 1.3649x over previous
//
#include <hip/hip_runtime.h>

#define D 8
#define NE 4
#define NS 3
#define NI 5
#define LN_EPS 1e-5f

// ---------------------------------------------------------------------------
// Setup kernel: C[s][n][d] = bproj[s][d] + sum_ij Bmat[s][n][i][j]*Wproj[s][d][i*8+j]
// Row-independent, 96 values into d_ws.
// ---------------------------------------------------------------------------
__global__ void precompute_C_kernel(const float* __restrict__ Bmat,
                                    const float* __restrict__ Wproj,
                                    const float* __restrict__ bproj,
                                    float* __restrict__ C) {
    int idx = threadIdx.x;
    if (idx >= NS * NE * D) return;
    int s = idx / (NE * D);
    int rem = idx % (NE * D);
    int n = rem / D;
    int d = rem % D;
    const float* bm = Bmat + ((size_t)s * NE + n) * 64;
    const float* wp = Wproj + ((size_t)s * D + d) * 64;
    float acc = bproj[s * D + d];
    #pragma unroll
    for (int k = 0; k < 64; ++k) acc += bm[k] * wp[k];
    C[idx] = acc;
}

__device__ __forceinline__ float fast_tanh(float x) {
    // tanh(x) = 1 - 2/(e^{2x}+1); stable at +/-inf via rcp(inf)=0, rcp(1)=1.
    float e = __expf(2.f * x);
    return 1.f - 2.f * __builtin_amdgcn_rcpf(e + 1.f);
}

// ---------------------------------------------------------------------------
// Main kernel: one thread per row. E/H in registers; per-row t-matrix staged
// in LDS as [chunk 0..15][tid] float4 (lane-consecutive 16B -> conflict-free
// ds_read_b128). souts reuses the same LDS after a barrier.
// ---------------------------------------------------------------------------
__global__ __launch_bounds__(256, 2) void whisp_kernel(
    const float* __restrict__ cl, const float* __restrict__ cd,
    const float* __restrict__ re_log, const float* __restrict__ mach,
    const float* __restrict__ alpha, const float* __restrict__ u,
    const float* __restrict__ We, const float* __restrict__ be,
    const float* __restrict__ Wproj,
    const float* __restrict__ Wr1, const float* __restrict__ br1,
    const float* __restrict__ Wr2, const float* __restrict__ br2,
    const float* __restrict__ ln_g, const float* __restrict__ ln_b,
    const float* __restrict__ Wout, const float* __restrict__ bout,
    const float* __restrict__ fg, const float* __restrict__ fb,
    const float* __restrict__ Wcst, const float* __restrict__ bcst,
    const float* __restrict__ Wcl, const float* __restrict__ bcl,
    const float* __restrict__ Cpre,
    float* __restrict__ out, int B)
{
    __shared__ float4 tbuf[16 * 256];   // 64 KB; t-matrix, later reused as souts

    const int tid = threadIdx.x;
    const int row = blockIdx.x * 256 + tid;
    const bool active = (row < B);

    float E[NE][D];
    float zout[19];

    if (active) {
        // ---- per-row inputs ----
        float uu[D];
        {
            const float4* up = reinterpret_cast<const float4*>(u + (size_t)row * D);
            float4 u0 = up[0], u1 = up[1];
            uu[0] = u0.x; uu[1] = u0.y; uu[2] = u0.z; uu[3] = u0.w;
            uu[4] = u1.x; uu[5] = u1.y; uu[6] = u1.z; uu[7] = u1.w;
        }
        float xs[NE] = { cl[row], cd[row], re_log[row], mach[row] };
        float al = alpha[row];

        // ---- embedding ----
        #pragma unroll
        for (int n = 0; n < NE; ++n) {
            #pragma unroll
            for (int d = 0; d < D; ++d) {
                float pre = We[n * 16 + d * 2 + 0] * xs[n]
                          + We[n * 16 + d * 2 + 1] * al
                          + be[n * D + d];
                E[n][d] = fast_tanh(pre);
            }
        }

        // ---- outer stages ----
        for (int s = 0; s < NS; ++s) {
            const float* Wp = Wproj + (size_t)s * D * 64;
            const float* W1 = Wr1 + s * 64;
            const float* B1 = br1 + s * D;
            const float* W2 = Wr2 + s * (NE * D);
            const float* B2 = br2 + s * NE;
            const float* Cs = Cpre + s * (NE * D);

            // t[d][i] = sum_j u[j]*Wp[d][i*8+j]  -> LDS chunks [2d],[2d+1]
            #pragma unroll
            for (int d = 0; d < D; ++d) {
                float tv[D];
                #pragma unroll
                for (int i = 0; i < D; ++i) {
                    const float* w = Wp + d * 64 + i * 8;
                    float a0 = uu[0] * w[0];
                    float a1 = uu[1] * w[1];
                    a0 = fmaf(uu[2], w[2], a0);
                    a1 = fmaf(uu[3], w[3], a1);
                    a0 = fmaf(uu[4], w[4], a0);
                    a1 = fmaf(uu[5], w[5], a1);
                    a0 = fmaf(uu[6], w[6], a0);
                    a1 = fmaf(uu[7], w[7], a1);
                    tv[i] = a0 + a1;
                }
                tbuf[(2 * d) * 256 + tid]     = make_float4(tv[0], tv[1], tv[2], tv[3]);
                tbuf[(2 * d + 1) * 256 + tid] = make_float4(tv[4], tv[5], tv[6], tv[7]);
            }

            for (int it = 0; it < NI; ++it) {
                // H[n][d] = C[n][d] + sum_i E[n][i]*t[d][i]
                float H[NE][D];
                #pragma unroll
                for (int d = 0; d < D; ++d) {
                    float4 ta = tbuf[(2 * d) * 256 + tid];
                    float4 tb = tbuf[(2 * d + 1) * 256 + tid];
                    #pragma unroll
                    for (int n = 0; n < NE; ++n) {
                        float a0 = fmaf(E[n][0], ta.x, Cs[n * D + d]);
                        float a1 = E[n][1] * ta.y;
                        a0 = fmaf(E[n][2], ta.z, a0);
                        a1 = fmaf(E[n][3], ta.w, a1);
                        a0 = fmaf(E[n][4], tb.x, a0);
                        a1 = fmaf(E[n][5], tb.y, a1);
                        a0 = fmaf(E[n][6], tb.z, a0);
                        a1 = fmaf(E[n][7], tb.w, a1);
                        H[n][d] = a0 + a1;
                    }
                }
                // routing softmax per n
                float sm[NE][NE];
                #pragma unroll
                for (int n = 0; n < NE; ++n) {
                    float r[D];
                    #pragma unroll
                    for (int d = 0; d < D; ++d) {
                        float a0 = fmaf(H[n][0], W1[d * D + 0], B1[d]);
                        float a1 = H[n][1] * W1[d * D + 1];
                        a0 = fmaf(H[n][2], W1[d * D + 2], a0);
                        a1 = fmaf(H[n][3], W1[d * D + 3], a1);
                        a0 = fmaf(H[n][4], W1[d * D + 4], a0);
                        a1 = fmaf(H[n][5], W1[d * D + 5], a1);
                        a0 = fmaf(H[n][6], W1[d * D + 6], a0);
                        a1 = fmaf(H[n][7], W1[d * D + 7], a1);
                        r[d] = fmaxf(a0 + a1, 0.f);
                    }
                    float lg[NE];
                    #pragma unroll
                    for (int e = 0; e < NE; ++e) {
                        float a0 = fmaf(r[0], W2[e * D + 0], B2[e]);
                        float a1 = r[1] * W2[e * D + 1];
                        a0 = fmaf(r[2], W2[e * D + 2], a0);
                        a1 = fmaf(r[3], W2[e * D + 3], a1);
                        a0 = fmaf(r[4], W2[e * D + 4], a0);
                        a1 = fmaf(r[5], W2[e * D + 5], a1);
                        a0 = fmaf(r[6], W2[e * D + 6], a0);
                        a1 = fmaf(r[7], W2[e * D + 7], a1);
                        lg[e] = a0 + a1;
                    }
                    float mx = fmaxf(fmaxf(lg[0], lg[1]), fmaxf(lg[2], lg[3]));
                    float e0 = __expf(lg[0] - mx), e1 = __expf(lg[1] - mx);
                    float e2 = __expf(lg[2] - mx), e3 = __expf(lg[3] - mx);
                    float inv = __builtin_amdgcn_rcpf((e0 + e1) + (e2 + e3));
                    sm[n][0] = e0 * inv; sm[n][1] = e1 * inv;
                    sm[n][2] = e2 * inv; sm[n][3] = e3 * inv;
                }
                // E += mix
                #pragma unroll
                for (int n = 0; n < NE; ++n) {
                    #pragma unroll
                    for (int d = 0; d < D; ++d) {
                        float a0 = fmaf(sm[n][0], H[0][d], E[n][d]);
                        float a1 = sm[n][1] * H[1][d];
                        a0 = fmaf(sm[n][2], H[2][d], a0);
                        a1 = fmaf(sm[n][3], H[3][d], a1);
                        E[n][d] = a0 + a1;
                    }
                }
            }

            // post-stage LayerNorm per embedding n
            #pragma unroll
            for (int n = 0; n < NE; ++n) {
                float m = 0.f;
                #pragma unroll
                for (int d = 0; d < D; ++d) m += E[n][d];
                m *= (1.f / D);
                float v = 0.f;
                #pragma unroll
                for (int d = 0; d < D; ++d) { float c = E[n][d] - m; v = fmaf(c, c, v); }
                v *= (1.f / D);
                float inv = __builtin_amdgcn_rsqf(v + LN_EPS);
                #pragma unroll
                for (int d = 0; d < D; ++d)
                    E[n][d] = (E[n][d] - m) * inv * ln_g[d] + ln_b[d];
            }
        }

        // ---- final mixing ----
        float lg[NE];
        #pragma unroll
        for (int e = 0; e < NE; ++e) {
            float a0 = bout[e], a1 = 0.f;
            #pragma unroll
            for (int n = 0; n < NE; ++n) {
                #pragma unroll
                for (int d = 0; d < D; d += 2) {
                    a0 = fmaf(E[n][d],     Wout[e * 32 + n * D + d],     a0);
                    a1 = fmaf(E[n][d + 1], Wout[e * 32 + n * D + d + 1], a1);
                }
            }
            lg[e] = a0 + a1;
        }
        float mx = fmaxf(fmaxf(lg[0], lg[1]), fmaxf(lg[2], lg[3]));
        float w0 = __expf(lg[0] - mx), w1 = __expf(lg[1] - mx);
        float w2 = __expf(lg[2] - mx), w3 = __expf(lg[3] - mx);
        float winv = __builtin_amdgcn_rcpf((w0 + w1) + (w2 + w3));
        w0 *= winv; w1 *= winv; w2 *= winv; w3 *= winv;

        float z[D];
        #pragma unroll
        for (int d = 0; d < D; ++d) {
            float a0 = fmaf(w0, E[0][d], 0.f);
            float a1 = w1 * E[1][d];
            a0 = fmaf(w2, E[2][d], a0);
            a1 = fmaf(w3, E[3][d], a1);
            z[d] = a0 + a1;
        }
        float zm = 0.f;
        #pragma unroll
        for (int d = 0; d < D; ++d) zm += z[d];
        zm *= (1.f / D);
        float zv = 0.f;
        #pragma unroll
        for (int d = 0; d < D; ++d) { float c = z[d] - zm; zv = fmaf(c, c, zv); }
        zv *= (1.f / D);
        float zinv = __builtin_amdgcn_rsqf(zv + LN_EPS);
        #pragma unroll
        for (int d = 0; d < D; ++d)
            z[d] = (z[d] - zm) * zinv * fg[d] + fb[d];

        // heads
        #pragma unroll
        for (int k = 0; k < 18; ++k) {
            float a0 = bcst[k], a1 = 0.f;
            #pragma unroll
            for (int d = 0; d < D; d += 2) {
                a0 = fmaf(z[d],     Wcst[k * D + d],     a0);
                a1 = fmaf(z[d + 1], Wcst[k * D + d + 1], a1);
            }
            zout[k] = a0 + a1;
        }
        {
            float a0 = bcl[0], a1 = 0.f;
            #pragma unroll
            for (int d = 0; d < D; d += 2) {
                a0 = fmaf(z[d],     Wcl[d],     a0);
                a1 = fmaf(z[d + 1], Wcl[d + 1], a1);
            }
            zout[18] = a0 + a1;
        }
    }

    // tbuf (t-matrix) is dead; reuse as souts. Barrier so no thread is still
    // reading its t chunks while another thread's souts write lands there.
    __syncthreads();
    float* souts = reinterpret_cast<float*>(tbuf);
    if (active) {
        #pragma unroll
        for (int k = 0; k < 19; ++k) souts[tid * 19 + k] = zout[k];
    }
    __syncthreads();

    // coalesced writeback of this block's 256x19 outputs
    const int base = blockIdx.x * 256;
    int nrows = B - base;
    if (nrows > 256) nrows = 256;
    if (nrows > 0) {
        const int cnt = nrows * 19;
        for (int i = tid; i < cnt; i += 256)
            out[(size_t)base * 19 + i] = souts[i];
    }
}

extern "C" void kernel_launch(void* const* d_in, const int* in_sizes, int n_in,
                              void* d_out, int out_size, void* d_ws, size_t ws_size,
                              hipStream_t stream) {
    const float* cl     = (const float*)d_in[0];
    const float* cd     = (const float*)d_in[1];
    const float* re_log = (const float*)d_in[2];
    const float* mach   = (const float*)d_in[3];
    const float* alpha  = (const float*)d_in[4];
    const float* u      = (const float*)d_in[5];
    const float* We     = (const float*)d_in[6];
    const float* be     = (const float*)d_in[7];
    const float* Bmat   = (const float*)d_in[8];
    const float* Wproj  = (const float*)d_in[9];
    const float* bproj  = (const float*)d_in[10];
    const float* Wr1    = (const float*)d_in[11];
    const float* br1    = (const float*)d_in[12];
    const float* Wr2    = (const float*)d_in[13];
    const float* br2    = (const float*)d_in[14];
    const float* ln_g   = (const float*)d_in[15];
    const float* ln_b   = (const float*)d_in[16];
    const float* Wout   = (const float*)d_in[17];
    const float* bout   = (const float*)d_in[18];
    const float* fg     = (const float*)d_in[19];
    const float* fb     = (const float*)d_in[20];
    const float* Wcst   = (const float*)d_in[21];
    const float* bcst   = (const float*)d_in[22];
    const float* Wcl    = (const float*)d_in[23];
    const float* bcl    = (const float*)d_in[24];

    float* Cpre = (float*)d_ws;   // 96 floats
    const int B = in_sizes[0];

    hipLaunchKernelGGL(precompute_C_kernel, dim3(1), dim3(128), 0, stream,
                       Bmat, Wproj, bproj, Cpre);

    const int blocks = (B + 255) / 256;
    hipLaunchKernelGGL(whisp_kernel, dim3(blocks), dim3(256), 0, stream,
                       cl, cd, re_log, mach, alpha, u, We, be, Wproj,
                       Wr1, br1, Wr2, br2, ln_g, ln_b, Wout, bout, fg, fb,
                       Wcst, bcst, Wcl, bcl, Cpre, (float*)d_out, B);
}